// Round 1
// baseline (3299.810 us; speedup 1.0000x reference)
//
#include <hip/hip_runtime.h>
#include <cstdint>

// Problem constants (EnBaseLayer: E(n)-GNN layer)
#define NN 50000      // nodes
#define NE 600000     // edges
#define HD 128        // hidden
#define NG 20         // gaussian smearing bins
#define EF 4          // edge_attr features
#define K1 280        // 2H + NG + EF  (edge MLP input dim)
#define WPB 16        // waves per block
#define BLOCK 1024
#define GRID 256
#define NWAVES (GRID*WPB)

// bf16-pair helpers: LDS holds uint32 = (bf16 lo = value A, bf16 hi = value B)
__device__ __forceinline__ float bf_lo(uint32_t w){ return __uint_as_float(w << 16); }
__device__ __forceinline__ float bf_hi(uint32_t w){ return __uint_as_float(w & 0xFFFF0000u); }
__device__ __forceinline__ uint32_t pack_bf16(float a, float b){
  uint32_t ua = __float_as_uint(a); ua += 0x7FFFu + ((ua >> 16) & 1u);  // RNE
  uint32_t ub = __float_as_uint(b); ub += 0x7FFFu + ((ub >> 16) & 1u);
  return (ua >> 16) | (ub & 0xFFFF0000u);
}
__device__ __forceinline__ float fast_rcp(float x){ return __builtin_amdgcn_rcpf(x); }
__device__ __forceinline__ float silu_f(float x){ return x * fast_rcp(1.0f + __expf(-x)); }
__device__ __forceinline__ float sigmoid_f(float x){ return fast_rcp(1.0f + __expf(-x)); }
__device__ __forceinline__ float tanh_f(float x){ return 1.0f - 2.0f * fast_rcp(__expf(2.0f*x) + 1.0f); }

// LDS sizes (bytes)
#define EDGE_LDS_U32 (K1*64 + HD*64 + HD*64 + WPB*K1)   // We1, We2, Wx1, per-wave inp
#define NODE_LDS_U32 (256*64 + HD*64 + WPB*256)         // Wn1, Wn2, per-wave cat
#define EDGE_LDS_B (EDGE_LDS_U32*4)
#define NODE_LDS_B (NODE_LDS_U32*4)

// ---------------------------------------------------------------------------
// Edge kernel: fused edge_mlp -> edge_inf -> x_mlp gate; atomically accumulates
// mi into out[0..NN*HD) and delta_x into out[NN*HD..NN*HD+NN*3).
// One wave processes 2 edges at a time; lane owns output channels (2l, 2l+1).
// ---------------------------------------------------------------------------
__global__ void __launch_bounds__(BLOCK) edge_kernel(
    const float* __restrict__ h, const float* __restrict__ x,
    const int* __restrict__ ei, const float* __restrict__ eattr,
    const float* __restrict__ We1, const float* __restrict__ be1,
    const float* __restrict__ We2, const float* __restrict__ be2,
    const float* __restrict__ Winf, const float* __restrict__ binf,
    const float* __restrict__ Wx1, const float* __restrict__ bx1,
    const float* __restrict__ Wx2, float* __restrict__ out)
{
  extern __shared__ uint32_t smem[];
  uint32_t* s_we1 = smem;                 // [K1][64] pairs over output channel
  uint32_t* s_we2 = s_we1 + K1*64;        // [HD][64]
  uint32_t* s_wx1 = s_we2 + HD*64;        // [HD][64]
  uint32_t* s_inp = s_wx1 + HD*64;        // [WPB][K1] pairs over the 2 edges

  const int tid = threadIdx.x;
  // ---- stage weights as bf16 pairs (once per block) ----
  for (int p = tid; p < K1*64; p += BLOCK) {
    const int k = p >> 6, l = p & 63;
    const float2 f = *reinterpret_cast<const float2*>(We1 + k*HD + 2*l);
    s_we1[p] = pack_bf16(f.x, f.y);
  }
  for (int p = tid; p < HD*64; p += BLOCK) {
    const int k = p >> 6, l = p & 63;
    const float2 f = *reinterpret_cast<const float2*>(We2 + k*HD + 2*l);
    s_we2[p] = pack_bf16(f.x, f.y);
    const float2 g2 = *reinterpret_cast<const float2*>(Wx1 + k*HD + 2*l);
    s_wx1[p] = pack_bf16(g2.x, g2.y);
  }
  __syncthreads();

  const int wave = tid >> 6, lane = tid & 63;
  uint32_t* winp = s_inp + wave * K1;
  const int o0 = 2*lane, o1 = o0 + 1;
  // hoisted per-lane constants
  const float vbe1_0 = be1[o0], vbe1_1 = be1[o1];
  const float vbe2_0 = be2[o0], vbe2_1 = be2[o1];
  const float vbx1_0 = bx1[o0], vbx1_1 = bx1[o1];
  const float vwinf0 = Winf[o0], vwinf1 = Winf[o1];
  const float vwx2_0 = Wx2[o0],  vwx2_1 = Wx2[o1];
  const float vbinf  = binf[0];

  for (int g = blockIdx.x*WPB + wave; g < NE/2; g += NWAVES) {
    const int e0 = 2*g, e1 = e0 + 1;
    const int s0 = ei[e0], s1 = ei[e1];
    const int d0 = ei[NE + e0], d1 = ei[NE + e1];
    // rel_x = x[dst] - x[src]; dist = sqrt(|rel|^2 + 1e-8)  (redundant per lane)
    const float rx0 = x[d0*3+0]-x[s0*3+0], ry0 = x[d0*3+1]-x[s0*3+1], rz0 = x[d0*3+2]-x[s0*3+2];
    const float rx1 = x[d1*3+0]-x[s1*3+0], ry1 = x[d1*3+1]-x[s1*3+1], rz1 = x[d1*3+2]-x[s1*3+2];
    const float dist0 = sqrtf(rx0*rx0+ry0*ry0+rz0*rz0 + 1e-8f);
    const float dist1 = sqrtf(rx1*rx1+ry1*ry1+rz1*rz1 + 1e-8f);

    // build inp[280] for both edges: [hi=h[dst] | hj=h[src] | d_feat | edge_attr]
    winp[lane]       = pack_bf16(h[d0*HD + lane],      h[d1*HD + lane]);
    winp[64 + lane]  = pack_bf16(h[d0*HD + 64 + lane], h[d1*HD + 64 + lane]);
    winp[128 + lane] = pack_bf16(h[s0*HD + lane],      h[s1*HD + lane]);
    winp[192 + lane] = pack_bf16(h[s0*HD + 64 + lane], h[s1*HD + 64 + lane]);
    if (lane < NG) {
      const float sp = 10.0f/19.0f;
      const float off = lane * sp;
      const float coeff = -0.5f/(sp*sp);
      const float a0 = dist0 - off, a1 = dist1 - off;
      winp[256 + lane] = pack_bf16(__expf(coeff*a0*a0), __expf(coeff*a1*a1));
    } else if (lane < NG + EF) {
      const int j = lane - NG;
      winp[256 + lane] = pack_bf16(eattr[e0*EF + j], eattr[e1*EF + j]);
    }
    __builtin_amdgcn_wave_barrier();   // wave-synchronous LDS producer->consumer

    // ---- GEMM1: t1 = silu(inp @ We1 + be1) ----
    float a00=0.f,a01=0.f,a10=0.f,a11=0.f;   // [out o0/o1][edge 0/1]
    #pragma unroll 4
    for (int k = 0; k < K1; ++k) {
      const uint32_t w = s_we1[k*64 + lane];
      const uint32_t p = winp[k];
      const float w0 = bf_lo(w), w1 = bf_hi(w);
      const float p0 = bf_lo(p), p1 = bf_hi(p);
      a00 = fmaf(w0,p0,a00); a01 = fmaf(w0,p1,a01);
      a10 = fmaf(w1,p0,a10); a11 = fmaf(w1,p1,a11);
    }
    __builtin_amdgcn_wave_barrier();
    winp[o0] = pack_bf16(silu_f(a00 + vbe1_0), silu_f(a01 + vbe1_0));
    winp[o1] = pack_bf16(silu_f(a10 + vbe1_1), silu_f(a11 + vbe1_1));
    __builtin_amdgcn_wave_barrier();

    // ---- GEMM2: mij = silu(t1 @ We2 + be2) ----
    float b00=0.f,b01=0.f,b10=0.f,b11=0.f;
    #pragma unroll 4
    for (int k = 0; k < HD; ++k) {
      const uint32_t w = s_we2[k*64 + lane];
      const uint32_t p = winp[k];
      const float w0 = bf_lo(w), w1 = bf_hi(w);
      const float p0 = bf_lo(p), p1 = bf_hi(p);
      b00 = fmaf(w0,p0,b00); b01 = fmaf(w0,p1,b01);
      b10 = fmaf(w1,p0,b10); b11 = fmaf(w1,p1,b11);
    }
    const float m00 = silu_f(b00 + vbe2_0), m01 = silu_f(b01 + vbe2_0);
    const float m10 = silu_f(b10 + vbe2_1), m11 = silu_f(b11 + vbe2_1);

    // ---- eij = sigmoid(mij @ Winf + binf) : wave reduction over channels ----
    float q0 = m00*vwinf0 + m10*vwinf1;
    float q1 = m01*vwinf0 + m11*vwinf1;
    #pragma unroll
    for (int s = 32; s > 0; s >>= 1) { q0 += __shfl_xor(q0, s); q1 += __shfl_xor(q1, s); }
    const float eij0 = sigmoid_f(q0 + vbinf), eij1 = sigmoid_f(q1 + vbinf);

    // ---- mi[dst] += mij * eij ----
    atomicAdd(&out[d0*HD + o0], m00*eij0);
    atomicAdd(&out[d0*HD + o1], m10*eij0);
    atomicAdd(&out[d1*HD + o0], m01*eij1);
    atomicAdd(&out[d1*HD + o1], m11*eij1);

    // store mij for GEMM3 (reuse inp buffer)
    __builtin_amdgcn_wave_barrier();
    winp[o0] = pack_bf16(m00, m01);
    winp[o1] = pack_bf16(m10, m11);
    __builtin_amdgcn_wave_barrier();

    // ---- GEMM3: u = silu(mij @ Wx1 + bx1); gate = tanh(u @ Wx2) ----
    float c00=0.f,c01=0.f,c10=0.f,c11=0.f;
    #pragma unroll 4
    for (int k = 0; k < HD; ++k) {
      const uint32_t w = s_wx1[k*64 + lane];
      const uint32_t p = winp[k];
      const float w0 = bf_lo(w), w1 = bf_hi(w);
      const float p0 = bf_lo(p), p1 = bf_hi(p);
      c00 = fmaf(w0,p0,c00); c01 = fmaf(w0,p1,c01);
      c10 = fmaf(w1,p0,c10); c11 = fmaf(w1,p1,c11);
    }
    const float u00 = silu_f(c00 + vbx1_0), u01 = silu_f(c01 + vbx1_0);
    const float u10 = silu_f(c10 + vbx1_1), u11 = silu_f(c11 + vbx1_1);
    float g0 = u00*vwx2_0 + u10*vwx2_1;
    float g1 = u01*vwx2_0 + u11*vwx2_1;
    #pragma unroll
    for (int s = 32; s > 0; s >>= 1) { g0 += __shfl_xor(g0, s); g1 += __shfl_xor(g1, s); }
    const float gate0 = tanh_f(g0), gate1 = tanh_f(g1);

    // ---- delta_x[dst] += rel_x / (d+1) * gate  (lanes 0..5) ----
    if (lane < 6) {
      const int e = (lane >= 3) ? 1 : 0;
      const int c = lane - 3*e;
      const float rel = e ? (c==0?rx1:(c==1?ry1:rz1)) : (c==0?rx0:(c==1?ry0:rz0));
      const float dd  = e ? dist1 : dist0;
      const float gg  = e ? gate1 : gate0;
      const int   dn  = e ? d1 : d0;
      atomicAdd(&out[NN*HD + dn*3 + c], rel * fast_rcp(dd + 1.0f) * gg);
    }
  }
}

// ---------------------------------------------------------------------------
// Node kernel: h_new = h + Wn2(silu(Wn1 [mi,h] + bn1)) + bn2 (in-place over mi
// region of out), x_new = x + dx*mask (in-place over dx region of out).
// ---------------------------------------------------------------------------
__global__ void __launch_bounds__(BLOCK) node_kernel(
    const float* __restrict__ h, const float* __restrict__ x,
    const float* __restrict__ mask,
    const float* __restrict__ Wn1, const float* __restrict__ bn1,
    const float* __restrict__ Wn2, const float* __restrict__ bn2,
    float* __restrict__ out)
{
  extern __shared__ uint32_t smem[];
  uint32_t* s_wn1 = smem;              // [256][64]
  uint32_t* s_wn2 = s_wn1 + 256*64;    // [HD][64]
  uint32_t* s_cat = s_wn2 + HD*64;     // [WPB][256]

  const int tid = threadIdx.x;
  for (int p = tid; p < 256*64; p += BLOCK) {
    const int k = p >> 6, l = p & 63;
    const float2 f = *reinterpret_cast<const float2*>(Wn1 + k*HD + 2*l);
    s_wn1[p] = pack_bf16(f.x, f.y);
  }
  for (int p = tid; p < HD*64; p += BLOCK) {
    const int k = p >> 6, l = p & 63;
    const float2 f = *reinterpret_cast<const float2*>(Wn2 + k*HD + 2*l);
    s_wn2[p] = pack_bf16(f.x, f.y);
  }
  __syncthreads();

  const int wave = tid >> 6, lane = tid & 63;
  uint32_t* wcat = s_cat + wave*256;
  const int o0 = 2*lane, o1 = o0+1;
  const float vbn1_0 = bn1[o0], vbn1_1 = bn1[o1];
  const float vbn2_0 = bn2[o0], vbn2_1 = bn2[o1];

  for (int g = blockIdx.x*WPB + wave; g < NN/2; g += NWAVES) {
    const int n0 = 2*g, n1 = n0+1;
    // cat = [mi (from out), h]
    wcat[lane]      = pack_bf16(out[n0*HD+lane],      out[n1*HD+lane]);
    wcat[64+lane]   = pack_bf16(out[n0*HD+64+lane],   out[n1*HD+64+lane]);
    wcat[128+lane]  = pack_bf16(h[n0*HD+lane],        h[n1*HD+lane]);
    wcat[192+lane]  = pack_bf16(h[n0*HD+64+lane],     h[n1*HD+64+lane]);
    __builtin_amdgcn_wave_barrier();

    float a00=0.f,a01=0.f,a10=0.f,a11=0.f;
    #pragma unroll 4
    for (int k = 0; k < 256; ++k) {
      const uint32_t w = s_wn1[k*64 + lane];
      const uint32_t p = wcat[k];
      const float w0 = bf_lo(w), w1 = bf_hi(w);
      const float p0 = bf_lo(p), p1 = bf_hi(p);
      a00 = fmaf(w0,p0,a00); a01 = fmaf(w0,p1,a01);
      a10 = fmaf(w1,p0,a10); a11 = fmaf(w1,p1,a11);
    }
    __builtin_amdgcn_wave_barrier();
    wcat[o0] = pack_bf16(silu_f(a00 + vbn1_0), silu_f(a01 + vbn1_0));
    wcat[o1] = pack_bf16(silu_f(a10 + vbn1_1), silu_f(a11 + vbn1_1));
    __builtin_amdgcn_wave_barrier();

    float b00=0.f,b01=0.f,b10=0.f,b11=0.f;
    #pragma unroll 4
    for (int k = 0; k < HD; ++k) {
      const uint32_t w = s_wn2[k*64 + lane];
      const uint32_t p = wcat[k];
      const float w0 = bf_lo(w), w1 = bf_hi(w);
      const float p0 = bf_lo(p), p1 = bf_hi(p);
      b00 = fmaf(w0,p0,b00); b01 = fmaf(w0,p1,b01);
      b10 = fmaf(w1,p0,b10); b11 = fmaf(w1,p1,b11);
    }
    const float2 h0 = *reinterpret_cast<const float2*>(h + n0*HD + o0);
    const float2 h1 = *reinterpret_cast<const float2*>(h + n1*HD + o0);
    float2 r0; r0.x = h0.x + b00 + vbn2_0; r0.y = h0.y + b10 + vbn2_1;
    float2 r1; r1.x = h1.x + b01 + vbn2_0; r1.y = h1.y + b11 + vbn2_1;
    *reinterpret_cast<float2*>(out + n0*HD + o0) = r0;
    *reinterpret_cast<float2*>(out + n1*HD + o0) = r1;

    if (lane < 6) {
      const int e = (lane >= 3) ? 1 : 0;
      const int c = lane - 3*e;
      const int n = e ? n1 : n0;
      const float dxv = out[NN*HD + n*3 + c];
      out[NN*HD + n*3 + c] = x[n*3 + c] + dxv * mask[n];
    }
  }
}

extern "C" void kernel_launch(void* const* d_in, const int* in_sizes, int n_in,
                              void* d_out, int out_size, void* d_ws, size_t ws_size,
                              hipStream_t stream) {
  (void)in_sizes; (void)n_in; (void)d_ws; (void)ws_size;
  const float* h    = (const float*)d_in[0];
  const float* x    = (const float*)d_in[1];
  const int*   ei   = (const int*)  d_in[2];
  const float* mask = (const float*)d_in[3];
  const float* ea   = (const float*)d_in[4];
  const float* We1  = (const float*)d_in[5];
  const float* be1  = (const float*)d_in[6];
  const float* We2  = (const float*)d_in[7];
  const float* be2  = (const float*)d_in[8];
  const float* Winf = (const float*)d_in[9];
  const float* binf = (const float*)d_in[10];
  const float* Wx1  = (const float*)d_in[11];
  const float* bx1  = (const float*)d_in[12];
  const float* Wx2  = (const float*)d_in[13];
  const float* Wn1  = (const float*)d_in[14];
  const float* bn1  = (const float*)d_in[15];
  const float* Wn2  = (const float*)d_in[16];
  const float* bn2  = (const float*)d_in[17];
  float* out = (float*)d_out;

  // enable >64KB dynamic LDS (no-op if already allowed); host-side, capture-safe
  hipFuncSetAttribute(reinterpret_cast<const void*>(edge_kernel),
                      hipFuncAttributeMaxDynamicSharedMemorySize, EDGE_LDS_B);
  hipFuncSetAttribute(reinterpret_cast<const void*>(node_kernel),
                      hipFuncAttributeMaxDynamicSharedMemorySize, NODE_LDS_B);

  // out[0..NN*HD) accumulates mi; out[NN*HD..) accumulates delta_x
  hipMemsetAsync(d_out, 0, (size_t)out_size * sizeof(float), stream);

  edge_kernel<<<GRID, BLOCK, EDGE_LDS_B, stream>>>(
      h, x, ei, ea, We1, be1, We2, be2, Winf, binf, Wx1, bx1, Wx2, out);
  node_kernel<<<GRID, BLOCK, NODE_LDS_B, stream>>>(
      h, x, mask, Wn1, bn1, Wn2, bn2, out);
}

// Round 2
// 714.633 us; speedup vs baseline: 4.6175x; 4.6175x over previous
//
#include <hip/hip_runtime.h>
#include <hip/hip_bf16.h>
#include <cstdint>

// Problem constants (EnBaseLayer: E(n)-GNN layer)
#define NN 50000
#define NE 600000
#define HD 128
#define NG 20
#define EF 4
#define K1 280           // 2H + NG + EF
#define TILES (NE/64)    // 9375 tiles of 64 edges
#define EGRID 512        // 2 blocks/CU

typedef __attribute__((ext_vector_type(4))) float f32x4;
typedef __attribute__((ext_vector_type(8))) __bf16 bf16x8;
typedef __attribute__((ext_vector_type(4))) unsigned int u32x4;

__device__ __forceinline__ float fast_rcp(float x){ return __builtin_amdgcn_rcpf(x); }
__device__ __forceinline__ float silu_f(float x){ return x * fast_rcp(1.0f + __expf(-x)); }
__device__ __forceinline__ float sigmoid_f(float x){ return fast_rcp(1.0f + __expf(-x)); }
__device__ __forceinline__ float tanh_f(float x){ return 1.0f - 2.0f*fast_rcp(__expf(2.0f*x)+1.0f); }

// RNE f32->bf16 packing (proven numerics from round 1)
__device__ __forceinline__ uint32_t pk2(float a, float b){
  uint32_t ua = __float_as_uint(a); ua += 0x7FFFu + ((ua>>16)&1u);
  uint32_t ub = __float_as_uint(b); ub += 0x7FFFu + ((ub>>16)&1u);
  return (ua>>16) | (ub & 0xFFFF0000u);
}
__device__ __forceinline__ uint16_t bfb(float a){
  uint32_t ua = __float_as_uint(a); ua += 0x7FFFu + ((ua>>16)&1u);
  return (uint16_t)(ua>>16);
}
__device__ __forceinline__ f32x4 MF(u32x4 a, u32x4 b, f32x4 c){
  return __builtin_amdgcn_mfma_f32_16x16x32_bf16(
      __builtin_bit_cast(bf16x8, a), __builtin_bit_cast(bf16x8, b), c, 0, 0, 0);
}

// ---------------------------------------------------------------------------
// Edge kernel, MFMA version. Block = 4 waves, tile = 64 edges.
// Wave w owns output channels [32w, 32w+32) (2 N-tiles) for all 4 M-tiles.
// Weights live in registers as persistent MFMA B-fragments.
// A-frag layout: lane l holds row (l&15), k = 32*ks + 8*(l>>4) + j.
// D-frag layout (HW-verified): col = l&15, row = 4*(l>>4) + reg.
// t1f/mf_ LDS buffers hold activations pre-arranged in A-fragment layout:
//   [Mt][ks2][lane][8 bf16], consumer reads one ds_read_b128 per fragment.
// ---------------------------------------------------------------------------
__global__ void __launch_bounds__(256, 2) edge_kernel(
    const float* __restrict__ h, const float* __restrict__ x,
    const int* __restrict__ ei, const float* __restrict__ eattr,
    const float* __restrict__ We1, const float* __restrict__ be1,
    const float* __restrict__ We2, const float* __restrict__ be2,
    const float* __restrict__ Winf, const float* __restrict__ binf,
    const float* __restrict__ Wx1, const float* __restrict__ bx1,
    const float* __restrict__ Wx2, float* __restrict__ out)
{
  __shared__ int   s_src[64], s_dst[64];
  __shared__ float s_rel[64][3], s_dist[64];
  __shared__ float s_pe[64], s_pg[64];
  __shared__ __align__(16) uint16_t t1f[4][4][64][8];   // 16 KB
  __shared__ __align__(16) uint16_t mf_[4][4][64][8];   // 16 KB

  const int tid = threadIdx.x;
  const int w = tid >> 6, l = tid & 63;
  const int lo = l & 15, hi = l >> 4;

  // ---- persistent weight B-fragments (loaded once per block) ----
  // B-frag (nt, ks): lane l holds W[k = 32*ks + 8*(l>>4) + j][col = nt*16 + (l&15)]
  u32x4 B1[2][9], B2[2][4], B3[2][4];
  #pragma unroll
  for (int ntl = 0; ntl < 2; ++ntl){
    const int col = (2*w + ntl)*16 + lo;
    #pragma unroll
    for (int ks = 0; ks < 9; ++ks){
      float f[8];
      #pragma unroll
      for (int j = 0; j < 8; ++j){
        const int k = ks*32 + hi*8 + j;
        f[j] = (k < K1) ? We1[k*HD + col] : 0.0f;
      }
      B1[ntl][ks] = {pk2(f[0],f[1]), pk2(f[2],f[3]), pk2(f[4],f[5]), pk2(f[6],f[7])};
    }
    #pragma unroll
    for (int ks = 0; ks < 4; ++ks){
      float f2[8], f3[8];
      #pragma unroll
      for (int j = 0; j < 8; ++j){
        const int k = ks*32 + hi*8 + j;
        f2[j] = We2[k*HD + col];
        f3[j] = Wx1[k*HD + col];
      }
      B2[ntl][ks] = {pk2(f2[0],f2[1]), pk2(f2[2],f2[3]), pk2(f2[4],f2[5]), pk2(f2[6],f2[7])};
      B3[ntl][ks] = {pk2(f3[0],f3[1]), pk2(f3[2],f3[3]), pk2(f3[4],f3[5]), pk2(f3[6],f3[7])};
    }
  }
  const int cA = 32*w + lo, cB = cA + 16;
  const float vbe1A = be1[cA], vbe1B = be1[cB];
  const float vbe2A = be2[cA], vbe2B = be2[cB];
  const float vbx1A = bx1[cA], vbx1B = bx1[cB];
  const float wiA = Winf[cA], wiB = Winf[cB];
  const float wxA = Wx2[cA],  wxB = Wx2[cB];
  const float vbinf = binf[0];
  const float SP = 10.0f/19.0f;
  const float CO = -0.5f/(SP*SP);

  for (int t = blockIdx.x; t < TILES; t += EGRID){
    const int ebase = t*64;
    __syncthreads();                    // protect LDS from prior-iter readers
    if (w == 0){                        // stage ids / rel / dist, zero partials
      const int e = ebase + l;
      const int sj = ei[e], dj = ei[NE + e];
      s_src[l] = sj; s_dst[l] = dj;
      const float ax = x[dj*3+0] - x[sj*3+0];
      const float ay = x[dj*3+1] - x[sj*3+1];
      const float az = x[dj*3+2] - x[sj*3+2];
      s_rel[l][0] = ax; s_rel[l][1] = ay; s_rel[l][2] = az;
      s_dist[l] = sqrtf(ax*ax + ay*ay + az*az + 1e-8f);
      s_pe[l] = 0.0f; s_pg[l] = 0.0f;
    }
    __syncthreads();

    // ---------------- GEMM1: t1 = silu(inp @ We1 + be1) ----------------
    #pragma unroll
    for (int Mt = 0; Mt < 4; ++Mt){
      const int r = Mt*16 + lo;          // A-row = edge within tile
      const int dn = s_dst[r], sn = s_src[r];
      f32x4 acc0 = {0,0,0,0}, acc1 = {0,0,0,0};
      #pragma unroll
      for (int ks = 0; ks < 8; ++ks){
        const float* hp = (ks < 4 ? h + (size_t)dn*HD + ks*32
                                  : h + (size_t)sn*HD + (ks-4)*32) + hi*8;
        const float4 va = *reinterpret_cast<const float4*>(hp);
        const float4 vb = *reinterpret_cast<const float4*>(hp + 4);
        u32x4 A = {pk2(va.x,va.y), pk2(va.z,va.w), pk2(vb.x,vb.y), pk2(vb.z,vb.w)};
        acc0 = MF(A, B1[0][ks], acc0);
        acc1 = MF(A, B1[1][ks], acc1);
      }
      { // ks = 8: gaussian smearing + edge_attr + zero pad
        const float dd = s_dist[r];
        float g[8];
        if (hi < 2){
          #pragma unroll
          for (int j = 0; j < 8; ++j){ const float a = dd - (hi*8+j)*SP; g[j] = __expf(CO*a*a); }
        } else if (hi == 2){
          #pragma unroll
          for (int j = 0; j < 4; ++j){ const float a = dd - (16+j)*SP; g[j] = __expf(CO*a*a); }
          const float4 e4 = *reinterpret_cast<const float4*>(eattr + (size_t)(ebase+r)*EF);
          g[4] = e4.x; g[5] = e4.y; g[6] = e4.z; g[7] = e4.w;
        } else {
          #pragma unroll
          for (int j = 0; j < 8; ++j) g[j] = 0.0f;
        }
        u32x4 A = {pk2(g[0],g[1]), pk2(g[2],g[3]), pk2(g[4],g[5]), pk2(g[6],g[7])};
        acc0 = MF(A, B1[0][8], acc0);
        acc1 = MF(A, B1[1][8], acc1);
      }
      // silu + write t1 into consumer A-fragment layout:
      //   value (edge e=4*hi+reg, chan c) -> t1f[Mt][c/32][e + 16*((c%32)/8)][c%8]
      const int jj  = lo & 7;
      const int lp0 = 4*hi + 16*(lo >> 3);        // ntl=0 -> c%32 = lo
      const int lp1 = 4*hi + 16*(2 + (lo >> 3));  // ntl=1 -> c%32 = 16+lo
      #pragma unroll
      for (int reg = 0; reg < 4; ++reg){
        t1f[Mt][w][lp0+reg][jj] = bfb(silu_f(acc0[reg] + vbe1A));
        t1f[Mt][w][lp1+reg][jj] = bfb(silu_f(acc1[reg] + vbe1B));
      }
    }
    __syncthreads();

    // ---------------- GEMM2: mij = silu(t1 @ We2 + be2) ----------------
    float mijA[4][4], mijB[4][4];
    #pragma unroll
    for (int Mt = 0; Mt < 4; ++Mt){
      f32x4 acc0 = {0,0,0,0}, acc1 = {0,0,0,0};
      #pragma unroll
      for (int ks = 0; ks < 4; ++ks){
        const u32x4 A = *reinterpret_cast<const u32x4*>(&t1f[Mt][ks][l][0]);
        acc0 = MF(A, B2[0][ks], acc0);
        acc1 = MF(A, B2[1][ks], acc1);
      }
      const int jj  = lo & 7;
      const int lp0 = 4*hi + 16*(lo >> 3);
      const int lp1 = 4*hi + 16*(2 + (lo >> 3));
      float p[4];
      #pragma unroll
      for (int reg = 0; reg < 4; ++reg){
        const float mA = silu_f(acc0[reg] + vbe2A);
        const float mB = silu_f(acc1[reg] + vbe2B);
        mijA[Mt][reg] = mA; mijB[Mt][reg] = mB;
        mf_[Mt][w][lp0+reg][jj] = bfb(mA);
        mf_[Mt][w][lp1+reg][jj] = bfb(mB);
        p[reg] = mA*wiA + mB*wiB;       // eij partial over this lane's 2 channels
      }
      #pragma unroll
      for (int m = 1; m < 16; m <<= 1){
        #pragma unroll
        for (int reg = 0; reg < 4; ++reg) p[reg] += __shfl_xor(p[reg], m);
      }
      if (lo == 0){
        #pragma unroll
        for (int reg = 0; reg < 4; ++reg) atomicAdd(&s_pe[Mt*16 + 4*hi + reg], p[reg]);
      }
    }
    __syncthreads();

    // ------------- eij + mi scatter, then GEMM3 gate partials -------------
    #pragma unroll
    for (int Mt = 0; Mt < 4; ++Mt){
      #pragma unroll
      for (int reg = 0; reg < 4; ++reg){
        const int r = Mt*16 + 4*hi + reg;           // D-row = edge
        const float eij = sigmoid_f(s_pe[r] + vbinf);
        float* op = out + (size_t)s_dst[r]*HD;
        atomicAdd(op + cA, mijA[Mt][reg]*eij);
        atomicAdd(op + cB, mijB[Mt][reg]*eij);
      }
    }
    #pragma unroll
    for (int Mt = 0; Mt < 4; ++Mt){
      f32x4 acc0 = {0,0,0,0}, acc1 = {0,0,0,0};
      #pragma unroll
      for (int ks = 0; ks < 4; ++ks){
        const u32x4 A = *reinterpret_cast<const u32x4*>(&mf_[Mt][ks][l][0]);
        acc0 = MF(A, B3[0][ks], acc0);
        acc1 = MF(A, B3[1][ks], acc1);
      }
      float p[4];
      #pragma unroll
      for (int reg = 0; reg < 4; ++reg){
        const float uA = silu_f(acc0[reg] + vbx1A);
        const float uB = silu_f(acc1[reg] + vbx1B);
        p[reg] = uA*wxA + uB*wxB;                   // gate partial
      }
      #pragma unroll
      for (int m = 1; m < 16; m <<= 1){
        #pragma unroll
        for (int reg = 0; reg < 4; ++reg) p[reg] += __shfl_xor(p[reg], m);
      }
      if (lo == 0){
        #pragma unroll
        for (int reg = 0; reg < 4; ++reg) atomicAdd(&s_pg[Mt*16 + 4*hi + reg], p[reg]);
      }
    }
    __syncthreads();

    // ------------- dx scatter: wave w handles M-tile w (48 lanes) -------------
    if (l < 48){
      const int e16 = l/3, comp = l - 3*e16;
      const int r = w*16 + e16;
      const float gate = tanh_f(s_pg[r]);
      const float sc = gate * fast_rcp(s_dist[r] + 1.0f);
      atomicAdd(out + (size_t)NN*HD + (size_t)s_dst[r]*3 + comp, s_rel[r][comp]*sc);
    }
  }
}

// ---------------------------------------------------------------------------
// Node kernel (unchanged from round 1): h_new = h + MLP([mi,h]) in-place over
// the mi region of out; x_new = x + dx*mask in-place over the dx region.
// ---------------------------------------------------------------------------
#define WPB 16
#define BLOCK 1024
#define NGRID 256
#define NNWAVES (NGRID*WPB)
#define NODE_LDS_U32 (256*64 + HD*64 + WPB*256)
#define NODE_LDS_B (NODE_LDS_U32*4)

__device__ __forceinline__ float bf_lo(uint32_t w){ return __uint_as_float(w << 16); }
__device__ __forceinline__ float bf_hi(uint32_t w){ return __uint_as_float(w & 0xFFFF0000u); }

__global__ void __launch_bounds__(BLOCK) node_kernel(
    const float* __restrict__ h, const float* __restrict__ x,
    const float* __restrict__ mask,
    const float* __restrict__ Wn1, const float* __restrict__ bn1,
    const float* __restrict__ Wn2, const float* __restrict__ bn2,
    float* __restrict__ out)
{
  extern __shared__ uint32_t smem[];
  uint32_t* s_wn1 = smem;              // [256][64]
  uint32_t* s_wn2 = s_wn1 + 256*64;    // [HD][64]
  uint32_t* s_cat = s_wn2 + HD*64;     // [WPB][256]

  const int tid = threadIdx.x;
  for (int p = tid; p < 256*64; p += BLOCK) {
    const int k = p >> 6, ll = p & 63;
    const float2 f = *reinterpret_cast<const float2*>(Wn1 + k*HD + 2*ll);
    s_wn1[p] = pk2(f.x, f.y);
  }
  for (int p = tid; p < HD*64; p += BLOCK) {
    const int k = p >> 6, ll = p & 63;
    const float2 f = *reinterpret_cast<const float2*>(Wn2 + k*HD + 2*ll);
    s_wn2[p] = pk2(f.x, f.y);
  }
  __syncthreads();

  const int wave = tid >> 6, lane = tid & 63;
  uint32_t* wcat = s_cat + wave*256;
  const int o0 = 2*lane, o1 = o0+1;
  const float vbn1_0 = bn1[o0], vbn1_1 = bn1[o1];
  const float vbn2_0 = bn2[o0], vbn2_1 = bn2[o1];

  for (int g = blockIdx.x*WPB + wave; g < NN/2; g += NNWAVES) {
    const int n0 = 2*g, n1 = n0+1;
    wcat[lane]      = pk2(out[n0*HD+lane],      out[n1*HD+lane]);
    wcat[64+lane]   = pk2(out[n0*HD+64+lane],   out[n1*HD+64+lane]);
    wcat[128+lane]  = pk2(h[n0*HD+lane],        h[n1*HD+lane]);
    wcat[192+lane]  = pk2(h[n0*HD+64+lane],     h[n1*HD+64+lane]);
    __builtin_amdgcn_wave_barrier();

    float a00=0.f,a01=0.f,a10=0.f,a11=0.f;
    #pragma unroll 4
    for (int k = 0; k < 256; ++k) {
      const uint32_t wv = s_wn1[k*64 + lane];
      const uint32_t p = wcat[k];
      const float w0 = bf_lo(wv), w1 = bf_hi(wv);
      const float p0 = bf_lo(p), p1 = bf_hi(p);
      a00 = fmaf(w0,p0,a00); a01 = fmaf(w0,p1,a01);
      a10 = fmaf(w1,p0,a10); a11 = fmaf(w1,p1,a11);
    }
    __builtin_amdgcn_wave_barrier();
    wcat[o0] = pk2(silu_f(a00 + vbn1_0), silu_f(a01 + vbn1_0));
    wcat[o1] = pk2(silu_f(a10 + vbn1_1), silu_f(a11 + vbn1_1));
    __builtin_amdgcn_wave_barrier();

    float b00=0.f,b01=0.f,b10=0.f,b11=0.f;
    #pragma unroll 4
    for (int k = 0; k < HD; ++k) {
      const uint32_t wv = s_wn2[k*64 + lane];
      const uint32_t p = wcat[k];
      const float w0 = bf_lo(wv), w1 = bf_hi(wv);
      const float p0 = bf_lo(p), p1 = bf_hi(p);
      b00 = fmaf(w0,p0,b00); b01 = fmaf(w0,p1,b01);
      b10 = fmaf(w1,p0,b10); b11 = fmaf(w1,p1,b11);
    }
    const float2 h0 = *reinterpret_cast<const float2*>(h + n0*HD + o0);
    const float2 h1 = *reinterpret_cast<const float2*>(h + n1*HD + o0);
    float2 r0; r0.x = h0.x + b00 + vbn2_0; r0.y = h0.y + b10 + vbn2_1;
    float2 r1; r1.x = h1.x + b01 + vbn2_0; r1.y = h1.y + b11 + vbn2_1;
    *reinterpret_cast<float2*>(out + n0*HD + o0) = r0;
    *reinterpret_cast<float2*>(out + n1*HD + o0) = r1;

    if (lane < 6) {
      const int e = (lane >= 3) ? 1 : 0;
      const int c = lane - 3*e;
      const int n = e ? n1 : n0;
      const float dxv = out[NN*HD + n*3 + c];
      out[NN*HD + n*3 + c] = x[n*3 + c] + dxv * mask[n];
    }
  }
}

extern "C" void kernel_launch(void* const* d_in, const int* in_sizes, int n_in,
                              void* d_out, int out_size, void* d_ws, size_t ws_size,
                              hipStream_t stream) {
  (void)in_sizes; (void)n_in; (void)d_ws; (void)ws_size;
  const float* h    = (const float*)d_in[0];
  const float* x    = (const float*)d_in[1];
  const int*   ei   = (const int*)  d_in[2];
  const float* mask = (const float*)d_in[3];
  const float* ea   = (const float*)d_in[4];
  const float* We1  = (const float*)d_in[5];
  const float* be1  = (const float*)d_in[6];
  const float* We2  = (const float*)d_in[7];
  const float* be2  = (const float*)d_in[8];
  const float* Winf = (const float*)d_in[9];
  const float* binf = (const float*)d_in[10];
  const float* Wx1  = (const float*)d_in[11];
  const float* bx1  = (const float*)d_in[12];
  const float* Wx2  = (const float*)d_in[13];
  const float* Wn1  = (const float*)d_in[14];
  const float* bn1  = (const float*)d_in[15];
  const float* Wn2  = (const float*)d_in[16];
  const float* bn2  = (const float*)d_in[17];
  float* out = (float*)d_out;

  hipFuncSetAttribute(reinterpret_cast<const void*>(node_kernel),
                      hipFuncAttributeMaxDynamicSharedMemorySize, NODE_LDS_B);

  // out[0..NN*HD) accumulates mi; out[NN*HD..) accumulates delta_x
  hipMemsetAsync(d_out, 0, (size_t)out_size * sizeof(float), stream);

  edge_kernel<<<EGRID, 256, 0, stream>>>(
      h, x, ei, ea, We1, be1, We2, be2, Winf, binf, Wx1, bx1, Wx2, out);
  node_kernel<<<NGRID, BLOCK, NODE_LDS_B, stream>>>(
      h, x, mask, Wn1, bn1, Wn2, bn2, out);
}

// Round 3
// 465.103 us; speedup vs baseline: 7.0948x; 1.5365x over previous
//
#include <hip/hip_runtime.h>
#include <hip/hip_bf16.h>
#include <cstdint>

// Problem constants (EnBaseLayer: E(n)-GNN layer)
#define NN 50000
#define NE 600000
#define HD 128
#define NG 20
#define EF 4
#define K1 280            // 2H + NG + EF
#define TILES (NE/64)     // 9375
#define EGRID 512         // 2 blocks/CU resident
#define ROWU 148          // s_inp row stride in u32 (592 B = 37*16, 16B-aligned rows)
#define NTILE 782         // ceil(NN/64)

typedef __attribute__((ext_vector_type(4))) float f32x4;
typedef __attribute__((ext_vector_type(8))) __bf16 bf16x8;
typedef __attribute__((ext_vector_type(4))) unsigned int u32x4;

__device__ __forceinline__ float fast_rcp(float x){ return __builtin_amdgcn_rcpf(x); }
__device__ __forceinline__ float silu_f(float x){ return x * fast_rcp(1.0f + __expf(-x)); }
__device__ __forceinline__ float sigmoid_f(float x){ return fast_rcp(1.0f + __expf(-x)); }
__device__ __forceinline__ float tanh_f(float x){ return 1.0f - 2.0f*fast_rcp(__expf(2.0f*x)+1.0f); }

__device__ __forceinline__ uint32_t pk2(float a, float b){   // RNE f32x2 -> bf16x2
  uint32_t ua = __float_as_uint(a); ua += 0x7FFFu + ((ua>>16)&1u);
  uint32_t ub = __float_as_uint(b); ub += 0x7FFFu + ((ub>>16)&1u);
  return (ua>>16) | (ub & 0xFFFF0000u);
}
__device__ __forceinline__ uint16_t bfb(float a){
  uint32_t ua = __float_as_uint(a); ua += 0x7FFFu + ((ua>>16)&1u);
  return (uint16_t)(ua>>16);
}
__device__ __forceinline__ float bf2f(uint16_t b){ return __uint_as_float(((uint32_t)b)<<16); }
__device__ __forceinline__ f32x4 MF(u32x4 a, u32x4 b, f32x4 c){
  return __builtin_amdgcn_mfma_f32_16x16x32_bf16(
      __builtin_bit_cast(bf16x8, a), __builtin_bit_cast(bf16x8, b), c, 0, 0, 0);
}

#define EDGE_LDS_U32 (64*ROWU + 4096 + 4096 + 448)
#define EDGE_LDS_B (EDGE_LDS_U32*4)   // 72448 B -> 2 blocks/CU

// ---------------------------------------------------------------------------
// Edge kernel: 8 waves/block, tile = 64 edges. Wave w owns N-tile w
// (channels 16w..16w+15). Input staged ONCE into LDS (bf16, frag-readable).
// A-frag: lane l holds row l&15, k = 32ks + 8*(l>>4) + j (j=0..7).
// D-frag: row(m)=4*(l>>4)+reg, col(n)=l&15  (HW-verified in round 2).
// ---------------------------------------------------------------------------
__global__ void __launch_bounds__(512, 4) edge_kernel(
    const float* __restrict__ h, const float* __restrict__ x,
    const int* __restrict__ ei, const float* __restrict__ eattr,
    const float* __restrict__ We1, const float* __restrict__ be1,
    const float* __restrict__ We2, const float* __restrict__ be2,
    const float* __restrict__ Winf, const float* __restrict__ binf,
    const float* __restrict__ Wx1, const float* __restrict__ bx1,
    const float* __restrict__ Wx2, float* __restrict__ out)
{
  extern __shared__ uint32_t smem[];
  uint32_t* s_inp = smem;                                   // [64][ROWU]
  uint16_t* t1f   = (uint16_t*)(smem + 64*ROWU);            // [4][4][64][8]
  uint16_t* mf_   = (uint16_t*)(smem + 64*ROWU + 4096);     // [4][4][64][8]
  uint32_t* tl    = smem + 64*ROWU + 8192;
  int*   s_dst  = (int*)tl;            // 64
  float* s_rel  = (float*)(tl+64);     // 192
  float* s_dist = (float*)(tl+256);    // 64
  float* s_pe   = (float*)(tl+320);    // 64
  float* s_pg   = (float*)(tl+384);    // 64

  const int tid = threadIdx.x;
  const int w = tid >> 6, l = tid & 63;
  const int lo = l & 15, hi = l >> 4;
  const int col = w*16 + lo;           // this lane's output channel

  // ---- persistent weight B-fragments (1 N-tile per wave: 17 frags = 68 VGPR)
  u32x4 B1[9], B2[4], B3[4];
  #pragma unroll
  for (int ks = 0; ks < 9; ++ks){
    float f[8];
    #pragma unroll
    for (int j = 0; j < 8; ++j){
      const int k = ks*32 + hi*8 + j;
      f[j] = (k < K1) ? We1[k*HD + col] : 0.0f;
    }
    B1[ks] = {pk2(f[0],f[1]), pk2(f[2],f[3]), pk2(f[4],f[5]), pk2(f[6],f[7])};
  }
  #pragma unroll
  for (int ks = 0; ks < 4; ++ks){
    float f2[8], f3[8];
    #pragma unroll
    for (int j = 0; j < 8; ++j){
      const int k = ks*32 + hi*8 + j;
      f2[j] = We2[k*HD + col];
      f3[j] = Wx1[k*HD + col];
    }
    B2[ks] = {pk2(f2[0],f2[1]), pk2(f2[2],f2[3]), pk2(f2[4],f2[5]), pk2(f2[6],f2[7])};
    B3[ks] = {pk2(f3[0],f3[1]), pk2(f3[2],f3[3]), pk2(f3[4],f3[5]), pk2(f3[6],f3[7])};
  }
  const float vbe1 = be1[col], vbe2 = be2[col], vbx1 = bx1[col];
  const float wi = Winf[col], wx = Wx2[col], vbinf = binf[0];
  const float SP = 10.0f/19.0f;
  const float CO = -0.5f/(SP*SP);
  const int r8 = tid >> 3, p8 = tid & 7;
  const int ks2 = w >> 1;
  const int lp  = ((w&1)*2 + (lo>>3))*16 + 4*hi;
  const int jj  = lo & 7;

  for (int t = blockIdx.x; t < TILES; t += EGRID){
    const int ebase = t*64;
    __syncthreads();                         // protect LDS from prior-iter readers

    // ---- phase A (64 threads): ids, rel, dist, gauss+attr cols, zero partials
    if (tid < 64){
      const int e = ebase + tid;
      const int sj = ei[e], dj = ei[NE + e];
      s_dst[tid] = dj;
      const float ax = x[dj*3+0]-x[sj*3+0];
      const float ay = x[dj*3+1]-x[sj*3+1];
      const float az = x[dj*3+2]-x[sj*3+2];
      const float dd = sqrtf(ax*ax + ay*ay + az*az + 1e-8f);
      s_rel[3*tid+0]=ax; s_rel[3*tid+1]=ay; s_rel[3*tid+2]=az;
      s_dist[tid]=dd; s_pe[tid]=0.0f; s_pg[tid]=0.0f;
      float g[32];
      #pragma unroll
      for (int j = 0; j < 20; ++j){ const float a = dd - j*SP; g[j] = __expf(CO*a*a); }
      const float4 e4 = *reinterpret_cast<const float4*>(eattr + (size_t)e*EF);
      g[20]=e4.x; g[21]=e4.y; g[22]=e4.z; g[23]=e4.w;
      #pragma unroll
      for (int j = 24; j < 32; ++j) g[j] = 0.0f;
      #pragma unroll
      for (int q = 0; q < 16; ++q) s_inp[tid*ROWU + 128 + q] = pk2(g[2*q], g[2*q+1]);
    }
    // ---- phase B (all 512 threads): gather h rows once, bf16-pack into LDS
    {
      const int e = ebase + r8;
      const int node = (p8 < 4) ? ei[NE + e] : ei[e];   // cols 0..127 = h[dst]
      const float* hp = h + (size_t)node*HD + (p8 & 3)*32;
      uint32_t* dp = s_inp + r8*ROWU + p8*16;
      #pragma unroll
      for (int q = 0; q < 8; ++q){
        const float4 v = *reinterpret_cast<const float4*>(hp + 4*q);
        dp[2*q]   = pk2(v.x, v.y);
        dp[2*q+1] = pk2(v.z, v.w);
      }
    }
    __syncthreads();

    // ---------------- GEMM1: t1 = silu(inp @ We1 + be1) ----------------
    #pragma unroll
    for (int Mt = 0; Mt < 4; ++Mt){
      const uint32_t* arow = s_inp + (Mt*16 + lo)*ROWU + hi*4;
      f32x4 acc = {0,0,0,0};
      #pragma unroll
      for (int ks = 0; ks < 9; ++ks){
        const u32x4 A = *reinterpret_cast<const u32x4*>(arow + ks*16);
        acc = MF(A, B1[ks], acc);
      }
      uint16_t* tp = t1f + ((Mt*4 + ks2)*64 + lp)*8 + jj;
      #pragma unroll
      for (int reg = 0; reg < 4; ++reg)
        tp[reg*8] = bfb(silu_f(acc[reg] + vbe1));
    }
    __syncthreads();

    // ---------------- GEMM2: mij = silu(t1 @ We2 + be2); eij partials ----
    #pragma unroll
    for (int Mt = 0; Mt < 4; ++Mt){
      f32x4 acc = {0,0,0,0};
      #pragma unroll
      for (int ks = 0; ks < 4; ++ks){
        const u32x4 A = *reinterpret_cast<const u32x4*>(t1f + ((Mt*4+ks)*64 + l)*8);
        acc = MF(A, B2[ks], acc);
      }
      uint16_t* mp = mf_ + ((Mt*4 + ks2)*64 + lp)*8 + jj;
      float p[4];
      #pragma unroll
      for (int reg = 0; reg < 4; ++reg){
        const float m = silu_f(acc[reg] + vbe2);
        mp[reg*8] = bfb(m);
        p[reg] = m * wi;
      }
      #pragma unroll
      for (int msk = 1; msk < 16; msk <<= 1){
        #pragma unroll
        for (int reg = 0; reg < 4; ++reg) p[reg] += __shfl_xor(p[reg], msk);
      }
      if (lo == 0){
        #pragma unroll
        for (int reg = 0; reg < 4; ++reg) atomicAdd(&s_pe[Mt*16 + 4*hi + reg], p[reg]);
      }
    }
    __syncthreads();

    // ---------------- mi scatter (reads mij back from LDS) ----------------
    #pragma unroll
    for (int Mt = 0; Mt < 4; ++Mt){
      #pragma unroll
      for (int reg = 0; reg < 4; ++reg){
        const int r = Mt*16 + 4*hi + reg;
        const float eij = sigmoid_f(s_pe[r] + vbinf);
        const float m = bf2f(mf_[((Mt*4 + ks2)*64 + lp + reg)*8 + jj]);
        atomicAdd(out + (size_t)s_dst[r]*HD + col, m*eij);
      }
    }
    // ---------------- GEMM3: gate partials ----------------
    #pragma unroll
    for (int Mt = 0; Mt < 4; ++Mt){
      f32x4 acc = {0,0,0,0};
      #pragma unroll
      for (int ks = 0; ks < 4; ++ks){
        const u32x4 A = *reinterpret_cast<const u32x4*>(mf_ + ((Mt*4+ks)*64 + l)*8);
        acc = MF(A, B3[ks], acc);
      }
      float p[4];
      #pragma unroll
      for (int reg = 0; reg < 4; ++reg)
        p[reg] = silu_f(acc[reg] + vbx1) * wx;
      #pragma unroll
      for (int msk = 1; msk < 16; msk <<= 1){
        #pragma unroll
        for (int reg = 0; reg < 4; ++reg) p[reg] += __shfl_xor(p[reg], msk);
      }
      if (lo == 0){
        #pragma unroll
        for (int reg = 0; reg < 4; ++reg) atomicAdd(&s_pg[Mt*16 + 4*hi + reg], p[reg]);
      }
    }
    __syncthreads();

    // ---------------- dx scatter ----------------
    if (tid < 192){
      const int er = tid/3, c = tid - 3*er;
      const float gate = tanh_f(s_pg[er]);
      const float sc = gate * fast_rcp(s_dist[er] + 1.0f);
      atomicAdd(out + (size_t)NN*HD + (size_t)s_dst[er]*3 + c, s_rel[3*er+c]*sc);
    }
  }
}

// ---------------------------------------------------------------------------
// Node kernel (MFMA): h_new = h + Wn2(silu(Wn1 [mi,h] + bn1)) + bn2, in-place
// over the mi region of out; x finalize in-place over the dx region.
// One 64-node tile per block; tail tile guarded.
// ---------------------------------------------------------------------------
#define CROW 132   // s_cat row stride in u32 (528 B = 33*16)

__global__ void __launch_bounds__(512, 4) node_kernel(
    const float* __restrict__ h, const float* __restrict__ x,
    const float* __restrict__ mask,
    const float* __restrict__ Wn1, const float* __restrict__ bn1,
    const float* __restrict__ Wn2, const float* __restrict__ bn2,
    float* __restrict__ out)
{
  __shared__ uint32_t s_cat[64*CROW];                  // 33.8 KB
  __shared__ __align__(16) uint16_t t1n[4*4*64*8];     // 16 KB

  const int tid = threadIdx.x;
  const int w = tid >> 6, l = tid & 63;
  const int lo = l & 15, hi = l >> 4;
  const int col = w*16 + lo;

  u32x4 Bn1[8], Bn2[4];
  #pragma unroll
  for (int ks = 0; ks < 8; ++ks){
    float f[8];
    #pragma unroll
    for (int j = 0; j < 8; ++j) f[j] = Wn1[(ks*32 + hi*8 + j)*HD + col];
    Bn1[ks] = {pk2(f[0],f[1]), pk2(f[2],f[3]), pk2(f[4],f[5]), pk2(f[6],f[7])};
  }
  #pragma unroll
  for (int ks = 0; ks < 4; ++ks){
    float f[8];
    #pragma unroll
    for (int j = 0; j < 8; ++j) f[j] = Wn2[(ks*32 + hi*8 + j)*HD + col];
    Bn2[ks] = {pk2(f[0],f[1]), pk2(f[2],f[3]), pk2(f[4],f[5]), pk2(f[6],f[7])};
  }
  const float vbn1 = bn1[col], vbn2 = bn2[col];
  const int nbase = blockIdx.x*64;
  const int ks2 = w >> 1;
  const int lp  = ((w&1)*2 + (lo>>3))*16 + 4*hi;
  const int jj  = lo & 7;

  // ---- staging: cat = [mi (from out), h], bf16-packed ----
  {
    const int r = tid >> 3, p = tid & 7;
    const int n = nbase + r;
    uint32_t* dp = s_cat + r*CROW + p*16;
    if (n < NN){
      const float* sp = (p < 4) ? (out + (size_t)n*HD + p*32)
                                : (h   + (size_t)n*HD + (p-4)*32);
      #pragma unroll
      for (int q = 0; q < 8; ++q){
        const float4 v = *reinterpret_cast<const float4*>(sp + 4*q);
        dp[2*q]   = pk2(v.x, v.y);
        dp[2*q+1] = pk2(v.z, v.w);
      }
    } else {
      #pragma unroll
      for (int q = 0; q < 16; ++q) dp[q] = 0u;
    }
  }
  __syncthreads();

  // ---- GEMM1 ----
  #pragma unroll
  for (int Mt = 0; Mt < 4; ++Mt){
    const uint32_t* arow = s_cat + (Mt*16 + lo)*CROW + hi*4;
    f32x4 acc = {0,0,0,0};
    #pragma unroll
    for (int ks = 0; ks < 8; ++ks){
      const u32x4 A = *reinterpret_cast<const u32x4*>(arow + ks*16);
      acc = MF(A, Bn1[ks], acc);
    }
    uint16_t* tp = t1n + ((Mt*4 + ks2)*64 + lp)*8 + jj;
    #pragma unroll
    for (int reg = 0; reg < 4; ++reg)
      tp[reg*8] = bfb(silu_f(acc[reg] + vbn1));
  }
  __syncthreads();

  // ---- GEMM2 + h_new write ----
  #pragma unroll
  for (int Mt = 0; Mt < 4; ++Mt){
    f32x4 acc = {0,0,0,0};
    #pragma unroll
    for (int ks = 0; ks < 4; ++ks){
      const u32x4 A = *reinterpret_cast<const u32x4*>(t1n + ((Mt*4+ks)*64 + l)*8);
      acc = MF(A, Bn2[ks], acc);
    }
    #pragma unroll
    for (int reg = 0; reg < 4; ++reg){
      const int n = nbase + Mt*16 + 4*hi + reg;
      if (n < NN)
        out[(size_t)n*HD + col] = h[(size_t)n*HD + col] + acc[reg] + vbn2;
    }
  }

  // ---- x finalize ----
  if (tid < 192){
    const int r = tid/3, c = tid - 3*r;
    const int n = nbase + r;
    if (n < NN){
      const size_t ix = (size_t)NN*HD + (size_t)n*3 + c;
      out[ix] = x[(size_t)n*3 + c] + out[ix]*mask[n];
    }
  }
}

extern "C" void kernel_launch(void* const* d_in, const int* in_sizes, int n_in,
                              void* d_out, int out_size, void* d_ws, size_t ws_size,
                              hipStream_t stream) {
  (void)in_sizes; (void)n_in; (void)d_ws; (void)ws_size;
  const float* h    = (const float*)d_in[0];
  const float* x    = (const float*)d_in[1];
  const int*   ei   = (const int*)  d_in[2];
  const float* mask = (const float*)d_in[3];
  const float* ea   = (const float*)d_in[4];
  const float* We1  = (const float*)d_in[5];
  const float* be1  = (const float*)d_in[6];
  const float* We2  = (const float*)d_in[7];
  const float* be2  = (const float*)d_in[8];
  const float* Winf = (const float*)d_in[9];
  const float* binf = (const float*)d_in[10];
  const float* Wx1  = (const float*)d_in[11];
  const float* bx1  = (const float*)d_in[12];
  const float* Wx2  = (const float*)d_in[13];
  const float* Wn1  = (const float*)d_in[14];
  const float* bn1  = (const float*)d_in[15];
  const float* Wn2  = (const float*)d_in[16];
  const float* bn2  = (const float*)d_in[17];
  float* out = (float*)d_out;

  hipFuncSetAttribute(reinterpret_cast<const void*>(edge_kernel),
                      hipFuncAttributeMaxDynamicSharedMemorySize, EDGE_LDS_B);

  // out[0..NN*HD) accumulates mi; out[NN*HD..) accumulates delta_x
  hipMemsetAsync(d_out, 0, (size_t)out_size * sizeof(float), stream);

  edge_kernel<<<EGRID, 512, EDGE_LDS_B, stream>>>(
      h, x, ei, ea, We1, be1, We2, be2, Winf, binf, Wx1, bx1, Wx2, out);
  node_kernel<<<NTILE, 512, 0, stream>>>(
      h, x, mask, Wn1, bn1, Wn2, bn2, out);
}